// Round 18
// baseline (70.393 us; speedup 1.0000x reference)
//
#include <hip/hip_runtime.h>
#include <math.h>

// FreqEmbedding: seq [16,512,64] f32 -> out [16,512,65,64] f32
// reflect-pad(64) -> hanning(128) frames -> rfft(128) -> complex standardize
// over (L,F) per (B,C) -> abs.
//
// Pass 0 (pad): materialize reflect-padded input [16,640,64]; zeroes acc.
// Pass A (reduce): Parseval identities (true-scale sums), f32 exact.
// Pass B (write): MFMA DFT. R4-R17 ledger: store path OK, I$ OK, loads OK,
//   occupancy OK -- the VALU FFT saturates ~44us regardless; MfmaUtil=0.
//   Replace FFT with GEMM on the IDLE matrix pipe:
//     X[f] = sum_n A'[f][n] * x[n],  A' = DFT*window, constant 130x128 f16
//   A' rows interleave {Re f, Im f} so each lane's D regs hold matching
//   Re/Im pairs -> standardize + abs with zero cross-lane ops.
//   144 x mfma_f32_16x16x32_f16 per frame; f32 accumulate; ~1e-3 abs err.

#define B_ 16
#define L_ 512
#define C_ 64
#define W_ 128
#define F_ 65
#define LP 640  // padded length
#define NLF (L_ * F_)  // 33280

typedef _Float16 half8 __attribute__((ext_vector_type(8)));
typedef float f32x4 __attribute__((ext_vector_type(4)));

// ---------- compile-time trig tables (fold to literals / .rodata) ----------
constexpr double kPI = 3.14159265358979323846;

constexpr double csin_(double x) {
  while (x > kPI) x -= 2.0 * kPI;
  while (x < -kPI) x += 2.0 * kPI;
  double t = x, s = x, x2 = x * x;
  for (int i = 1; i <= 24; ++i) {
    t *= -x2 / ((2.0 * i) * (2.0 * i + 1.0));
    s += t;
  }
  return s;
}
constexpr double ccos_(double x) { return csin_(kPI / 2.0 - x); }

struct Tables {
  float win[128];   // hanning w_n
  float walt[128];  // (-1)^n w_n
  float w2[128];    // w_n^2
  float wg[128];    // w_n * G_n
  constexpr Tables() : win(), walt(), w2(), wg() {
    for (int n = 0; n < 128; ++n) {
      const double wd = 0.5 - 0.5 * ccos_(2.0 * kPI * n / 127.0);
      win[n] = (float)wd;
      walt[n] = (n & 1) ? (float)(-wd) : (float)wd;
      w2[n] = (float)(wd * wd);
      if (n == 0) {
        wg[n] = 0.0f;
      } else {
        // G_n = sin(pi n/2) * sin(65 pi n/128) / sin(pi n/128)
        const double G = csin_(kPI * n / 2.0) * csin_(65.0 * kPI * n / 128.0) /
                         csin_(kPI * n / 128.0);
        wg[n] = (float)(wd * G);
      }
    }
  }
};
constexpr Tables TBL{};

// A' matrix: rows r=2f -> cos(2pi f n/128)*win[n]; r=2f+1 -> -sin(...)*win[n]
// f = 0..64 (rows 0..129); rows 130..143 zero. Angle reduced via (f*n) mod 128
// to keep constexpr step count low.
struct alignas(16) AMat {
  _Float16 a[144][128];
  constexpr AMat() : a() {
    double cs[128] = {}, sn[128] = {}, w[128] = {};
    for (int m = 0; m < 128; ++m) {
      cs[m] = ccos_(2.0 * kPI * m / 128.0);
      sn[m] = csin_(2.0 * kPI * m / 128.0);
    }
    for (int n = 0; n < 128; ++n)
      w[n] = 0.5 - 0.5 * ccos_(2.0 * kPI * n / 127.0);
    for (int f = 0; f <= 64; ++f)
      for (int n = 0; n < 128; ++n) {
        const int m = (f * n) & 127;
        a[2 * f][n] = (_Float16)(cs[m] * w[n]);
        a[2 * f + 1][n] = (_Float16)(-sn[m] * w[n]);
      }
  }
};
constexpr AMat AMT{};

// branchless reflect into [0,512) for t in [-64, 575]
__device__ __forceinline__ int refl(int t) {
  const int a = max(t, -t);
  return min(a, 1022 - a);
}

__device__ __forceinline__ float fast_sqrt(float x) {
  float r;
  asm("v_sqrt_f32 %0, %1" : "=v"(r) : "v"(x));
  return r;
}

// ---------------- Pass 0: pad materialize + acc zero ----------------
__global__ void __launch_bounds__(256)
fe_pad_kernel(const float* __restrict__ seq, float* __restrict__ pad,
              float* __restrict__ acc) {
  const int idx = blockIdx.x * 256 + threadIdx.x;  // b*LP*C + t*C + c
  if (idx < 3072) acc[idx] = 0.0f;  // zero accumulators (reduce runs after)
  const int c = idx & 63;
  const int row = idx >> 6;  // b*LP + t
  const int b = row / LP;
  const int t = row - b * LP;
  const int s = refl(t - 64);
  pad[idx] = seq[(b * L_ + s) * C_ + c];
}

// ws layout (floats): [0..1023] sum_re, [1024..2047] sum_im, [2048..3071] sum_sq,
//                     [4096 ..] padded input [16][640][64]
// ---------------- Pass A: Parseval reduce (f32 exact, true scale) ----------------
__global__ void __launch_bounds__(256)
fe_reduce_kernel(const float* __restrict__ pad, float* __restrict__ acc) {
  const int p = blockIdx.x * 4 + (threadIdx.x >> 6);
  const int b = __builtin_amdgcn_readfirstlane(p >> 9);
  const int l = __builtin_amdgcn_readfirstlane(p & (L_ - 1));
  const int c = threadIdx.x & 63;

  const float* base = pad + ((size_t)(b * LP + l)) * C_ + c;

  float2 a0 = make_float2(0.f, 0.f), a1 = a0, a2 = a0, a3 = a0;
#pragma unroll
  for (int n = 0; n < 64; ++n) {
    const float2 v = make_float2(base[(2 * n) * C_], base[(2 * n + 1) * C_]);
    a0.x = __builtin_fmaf(TBL.win[2 * n], v.x, a0.x);
    a0.y = __builtin_fmaf(TBL.win[2 * n + 1], v.y, a0.y);
    a1.x = __builtin_fmaf(TBL.walt[2 * n], v.x, a1.x);
    a1.y = __builtin_fmaf(TBL.walt[2 * n + 1], v.y, a1.y);
    const float2 wv = make_float2(TBL.w2[2 * n] * v.x, TBL.w2[2 * n + 1] * v.y);
    a2.x = __builtin_fmaf(wv.x, v.x, a2.x);
    a2.y = __builtin_fmaf(wv.y, v.y, a2.y);
    a3.x = __builtin_fmaf(TBL.wg[2 * n], v.x, a3.x);
    a3.y = __builtin_fmaf(TBL.wg[2 * n + 1], v.y, a3.y);
  }
  const float x0 = a0.x + a0.y;
  const float x64 = a1.x + a1.y;
  const float p2 = a2.x + a2.y;
  const float d2 = a3.x + a3.y;

  const float sre = 0.5f * (x0 + x64);
  const float sim = -d2;
  const float ssq = 64.0f * p2 + 0.5f * (x0 * x0 + x64 * x64);

  __shared__ float red[3][256];
  const int tid = threadIdx.x;
  red[0][tid] = sre;
  red[1][tid] = sim;
  red[2][tid] = ssq;
  __syncthreads();
  if (tid < 64) {
    const float a0s = red[0][tid] + red[0][tid + 64] + red[0][tid + 128] + red[0][tid + 192];
    const float a1s = red[1][tid] + red[1][tid + 64] + red[1][tid + 128] + red[1][tid + 192];
    const float a2s = red[2][tid] + red[2][tid + 64] + red[2][tid + 128] + red[2][tid + 192];
    const int g = b * C_ + tid;
    unsafeAtomicAdd(&acc[g], a0s);
    unsafeAtomicAdd(&acc[1024 + g], a1s);
    unsafeAtomicAdd(&acc[2048 + g], a2s);
  }
}

// ---------------- Pass B: MFMA DFT + standardize + write ----------------
__global__ void __launch_bounds__(256)
fe_write_kernel(const float* __restrict__ pad, const float* __restrict__ acc,
                float* __restrict__ out) {
  const int tid = threadIdx.x;
  const int p = blockIdx.x * 4 + (tid >> 6);
  const int b = __builtin_amdgcn_readfirstlane(p >> 9);
  const int l = __builtin_amdgcn_readfirstlane(p & (L_ - 1));
  const int lane = tid & 63;
  const int m16 = lane & 15;   // MFMA row/col within tile
  const int g8 = lane >> 4;    // K-group

  const float* pb = pad + (size_t)(b * LP + l) * C_;

  // ---- load 16 B-fragments: B[k][n], n = nt*16+m16 (channel), k strided ----
  // lane holds k = kk*32 + g8*8 + j, j=0..7 (linear pair packing)
  half8 bf[4][4];
#pragma unroll
  for (int kk = 0; kk < 4; ++kk) {
#pragma unroll
    for (int nt = 0; nt < 4; ++nt) {
      const float* q = pb + (kk * 32 + g8 * 8) * C_ + nt * 16 + m16;
      half8 v;
#pragma unroll
      for (int j = 0; j < 8; ++j) v[j] = (_Float16)q[j * C_];
      bf[kk][nt] = v;
    }
  }

  // ---- per-nt standardization constants (c = nt*16 + m16) ----
  float mr[4], mi[4], isv[4];
  const float invN = 1.0f / (float)NLF;
#pragma unroll
  for (int nt = 0; nt < 4; ++nt) {
    const int g = b * C_ + nt * 16 + m16;
    const float sr = acc[g] * invN;
    const float si = acc[1024 + g] * invN;
    const float qq = acc[2048 + g] * invN;
    mr[nt] = sr;
    mi[nt] = si;
    isv[nt] = rsqrtf(qq - sr * sr - si * si);
  }

  float* ob = out + ((size_t)(b * L_ + l) * F_) * C_;

  // ---- 9 M-tiles x 4 K-steps x 4 N-tiles of mfma_f32_16x16x32_f16 ----
#pragma unroll
  for (int mt = 0; mt < 9; ++mt) {
    f32x4 av[4] = {{0.f, 0.f, 0.f, 0.f},
                   {0.f, 0.f, 0.f, 0.f},
                   {0.f, 0.f, 0.f, 0.f},
                   {0.f, 0.f, 0.f, 0.f}};
#pragma unroll
    for (int kk = 0; kk < 4; ++kk) {
      const half8 af =
          *(const half8*)(&AMT.a[mt * 16 + m16][kk * 32 + g8 * 8]);
#pragma unroll
      for (int nt = 0; nt < 4; ++nt)
        av[nt] = __builtin_amdgcn_mfma_f32_16x16x32_f16(af, bf[kk][nt],
                                                        av[nt], 0, 0, 0);
    }
    // epilogue: D row = g8*4 + reg (global row mt*16 + ...):
    //   reg0 = Re X_f, reg1 = Im X_f, reg2 = Re X_{f+1}, reg3 = Im X_{f+1}
    //   with f = mt*8 + g8*2
    const int f0 = mt * 8 + g8 * 2;
#pragma unroll
    for (int nt = 0; nt < 4; ++nt) {
      const int co = nt * 16 + m16;
      {
        const float dr = av[nt][0] - mr[nt];
        const float di = av[nt][1] - mi[nt];
        const float amp = fast_sqrt(__builtin_fmaf(dr, dr, di * di)) * isv[nt];
        if (f0 < F_)
          __builtin_nontemporal_store(amp, ob + (size_t)f0 * C_ + co);
      }
      {
        const float dr = av[nt][2] - mr[nt];
        const float di = av[nt][3] - mi[nt];
        const float amp = fast_sqrt(__builtin_fmaf(dr, dr, di * di)) * isv[nt];
        if (f0 + 1 < F_)
          __builtin_nontemporal_store(amp, ob + (size_t)(f0 + 1) * C_ + co);
      }
    }
  }
}

extern "C" void kernel_launch(void* const* d_in, const int* in_sizes, int n_in,
                              void* d_out, int out_size, void* d_ws, size_t ws_size,
                              hipStream_t stream) {
  const float* seq = (const float*)d_in[0];
  float* out = (float*)d_out;
  float* ws = (float*)d_ws;
  float* acc = ws;          // 3072 floats
  float* pad = ws + 4096;   // 16*640*64 = 655360 floats (2.62 MB)

  // 3 dispatches total (memset folded into pad kernel)
  fe_pad_kernel<<<(B_ * LP * C_) / 256, 256, 0, stream>>>(seq, pad, acc);
  const int nblocks = (B_ * L_) / 4;  // 2048 blocks, 4 frames each
  fe_reduce_kernel<<<nblocks, 256, 0, stream>>>(pad, acc);
  fe_write_kernel<<<nblocks, 256, 0, stream>>>(pad, acc, out);
}

// Round 20
// 63.286 us; speedup vs baseline: 1.1123x; 1.1123x over previous
//
#include <hip/hip_runtime.h>
#include <hip/hip_fp16.h>
#include <math.h>

// FreqEmbedding: seq [16,512,64] f32 -> out [16,512,65,64] f32
// reflect-pad(64) -> hanning(128) frames -> rfft(128) -> complex standardize
// over (L,F) per (B,C) -> abs.
//
// Pass 0 (pad): materialize reflect-padded input [16,640,64]; zeroes acc.
// Pass A (reduce): Parseval identities, f32 exact (mu/sigma exact).
// Pass B (write): R17's f16-state monolithic FFT, UNCHANGED math, plus
//   R19/R20 OUTPUT REPACK: thread emits its 65 amps to an LDS tile; the
//   128-thread block (2 consecutive frames = one contiguous 33KB output
//   region) then drains LDS->global as ext-vector float4 (1KB/wave
//   contiguous, block-sequential). Theory: the old 65 x 256B wave-stores
//   at 16.6KB stride scatter the HBM line stream -> ~2.9 TB/s; contiguous
//   streams (fillBuffer) hit 6.6 TB/s. (R19 = compile fix: nontemporal
//   builtin needs ext_vector_type, not HIP_vector_type float4.)

#define B_ 16
#define L_ 512
#define C_ 64
#define W_ 128
#define F_ 65
#define LP 640  // padded length
#define NLF (L_ * F_)  // 33280

typedef float f32x4_t __attribute__((ext_vector_type(4)));

// ---------- compile-time trig tables (fold to VALU literals) ----------
constexpr double kPI = 3.14159265358979323846;

constexpr double csin_(double x) {
  while (x > kPI) x -= 2.0 * kPI;
  while (x < -kPI) x += 2.0 * kPI;
  double t = x, s = x, x2 = x * x;
  for (int i = 1; i <= 24; ++i) {
    t *= -x2 / ((2.0 * i) * (2.0 * i + 1.0));
    s += t;
  }
  return s;
}
constexpr double ccos_(double x) { return csin_(kPI / 2.0 - x); }

constexpr int bitrev6(int n) {
  int r = 0;
  for (int i = 0; i < 6; ++i) r |= ((n >> i) & 1) << (5 - i);
  return r;
}

struct Tables {
  float win[128];         // hanning w_n
  float walt[128];        // (-1)^n w_n
  float w2[128];          // w_n^2
  float wg[128];          // w_n * G_n
  float twr[32], twi[32]; // exp(-2*pi*i*j/64)
  float cur[32], cui[32]; // exp(-2*pi*i*k/128), k=0..31
  constexpr Tables() : win(), walt(), w2(), wg(), twr(), twi(), cur(), cui() {
    for (int n = 0; n < 128; ++n) {
      const double wd = 0.5 - 0.5 * ccos_(2.0 * kPI * n / 127.0);
      win[n] = (float)wd;
      walt[n] = (n & 1) ? (float)(-wd) : (float)wd;
      w2[n] = (float)(wd * wd);
      if (n == 0) {
        wg[n] = 0.0f;
      } else {
        // G_n = sin(pi n/2) * sin(65 pi n/128) / sin(pi n/128)
        const double G = csin_(kPI * n / 2.0) * csin_(65.0 * kPI * n / 128.0) /
                         csin_(kPI * n / 128.0);
        wg[n] = (float)(wd * G);
      }
    }
    for (int j = 0; j < 32; ++j) {
      twr[j] = (float)ccos_(2.0 * kPI * j / 64.0);
      twi[j] = (float)(-csin_(2.0 * kPI * j / 64.0));
    }
    for (int k = 0; k < 32; ++k) {
      cur[k] = (float)ccos_(2.0 * kPI * k / 128.0);
      cui[k] = (float)(-csin_(2.0 * kPI * k / 128.0));
    }
  }
};
constexpr Tables TBL{};

// branchless reflect into [0,512) for t in [-64, 575]
__device__ __forceinline__ int refl(int t) {
  const int a = max(t, -t);
  return min(a, 1022 - a);
}

__device__ __forceinline__ float fast_sqrt(float x) {
  float r;
  asm("v_sqrt_f32 %0, %1" : "=v"(r) : "v"(x));
  return r;
}

// packed f16 complex multiply: (wr + i*wi) * v, v = half2(re, im)
__device__ __forceinline__ __half2 chmul(float wr, float wi, __half2 v) {
  const __half2 w2r = __floats2half2_rn(wr, wr);     // literal
  const __half2 w2i = __floats2half2_rn(-wi, wi);    // literal
  const __half2 vsw = __lowhigh2highlow(v);          // (im, re)
  return __hfma2(w2i, vsw, __hmul2(w2r, v));
}

// ---------------- Pass 0: pad materialize + acc zero ----------------
__global__ void __launch_bounds__(256)
fe_pad_kernel(const float* __restrict__ seq, float* __restrict__ pad,
              float* __restrict__ acc) {
  const int idx = blockIdx.x * 256 + threadIdx.x;  // b*LP*C + t*C + c
  if (idx < 3072) acc[idx] = 0.0f;  // zero accumulators (reduce runs after)
  const int c = idx & 63;
  const int row = idx >> 6;  // b*LP + t
  const int b = row / LP;
  const int t = row - b * LP;
  const int s = refl(t - 64);
  pad[idx] = seq[(b * L_ + s) * C_ + c];
}

// ws layout (floats): [0..1023] sum_re, [1024..2047] sum_im, [2048..3071] sum_sq,
//                     [4096 ..] padded input [16][640][64]
// ---------------- Pass A: Parseval reduce (f32 exact) ----------------
__global__ void __launch_bounds__(256)
fe_reduce_kernel(const float* __restrict__ pad, float* __restrict__ acc) {
  const int p = blockIdx.x * 4 + (threadIdx.x >> 6);
  const int b = __builtin_amdgcn_readfirstlane(p >> 9);
  const int l = __builtin_amdgcn_readfirstlane(p & (L_ - 1));
  const int c = threadIdx.x & 63;

  const float* base = pad + ((size_t)(b * LP + l)) * C_ + c;

  float2 a0 = make_float2(0.f, 0.f), a1 = a0, a2 = a0, a3 = a0;
#pragma unroll
  for (int n = 0; n < 64; ++n) {
    const float2 v = make_float2(base[(2 * n) * C_], base[(2 * n + 1) * C_]);
    a0.x = __builtin_fmaf(TBL.win[2 * n], v.x, a0.x);
    a0.y = __builtin_fmaf(TBL.win[2 * n + 1], v.y, a0.y);
    a1.x = __builtin_fmaf(TBL.walt[2 * n], v.x, a1.x);
    a1.y = __builtin_fmaf(TBL.walt[2 * n + 1], v.y, a1.y);
    const float2 wv = make_float2(TBL.w2[2 * n] * v.x, TBL.w2[2 * n + 1] * v.y);
    a2.x = __builtin_fmaf(wv.x, v.x, a2.x);
    a2.y = __builtin_fmaf(wv.y, v.y, a2.y);
    a3.x = __builtin_fmaf(TBL.wg[2 * n], v.x, a3.x);
    a3.y = __builtin_fmaf(TBL.wg[2 * n + 1], v.y, a3.y);
  }
  const float x0 = a0.x + a0.y;
  const float x64 = a1.x + a1.y;
  const float p2 = a2.x + a2.y;
  const float d2 = a3.x + a3.y;

  const float sre = 0.5f * (x0 + x64);
  const float sim = -d2;
  const float ssq = 64.0f * p2 + 0.5f * (x0 * x0 + x64 * x64);

  __shared__ float red[3][256];
  const int tid = threadIdx.x;
  red[0][tid] = sre;
  red[1][tid] = sim;
  red[2][tid] = ssq;
  __syncthreads();
  if (tid < 64) {
    const float a0s = red[0][tid] + red[0][tid + 64] + red[0][tid + 128] + red[0][tid + 192];
    const float a1s = red[1][tid] + red[1][tid + 64] + red[1][tid + 128] + red[1][tid + 192];
    const float a2s = red[2][tid] + red[2][tid + 64] + red[2][tid + 128] + red[2][tid + 192];
    const int g = b * C_ + tid;
    unsafeAtomicAdd(&acc[g], a0s);
    unsafeAtomicAdd(&acc[1024 + g], a1s);
    unsafeAtomicAdd(&acc[2048 + g], a2s);
  }
}

// ---------------- Pass B: f16 FFT + LDS output repack ----------------
__global__ void __launch_bounds__(128)
fe_write_kernel(const float* __restrict__ pad, const float* __restrict__ acc,
                float* __restrict__ out) {
  __shared__ float lds_o[2 * F_ * C_];  // 2 frames x 65 x 64 = 33,280 B

  const int tid = threadIdx.x;
  const int wv = tid >> 6;              // frame within block (0,1)
  const int c = tid & 63;
  const int p0 = blockIdx.x * 2;
  const int b = __builtin_amdgcn_readfirstlane(p0 >> 9);
  const int l0 = __builtin_amdgcn_readfirstlane(p0 & (L_ - 1));
  const int l = l0 + wv;

  // fused finalize: true-scale sums -> constants matching the 2x bins
  const int g = b * C_ + c;
  const float invN = 1.0f / (float)NLF;
  const float sr = acc[g] * invN;
  const float si = acc[1024 + g] * invN;
  const float qq = acc[2048 + g] * invN;
  const float var = qq - sr * sr - si * si;
  const float2 mu = make_float2(2.0f * sr, 2.0f * si);
  const float is = 0.5f * rsqrtf(var);

  const float* base = pad + ((size_t)(b * LP + l)) * C_ + c;

  // ---- load in bit-reversed order, window in f32, pack to half2 ----
  __half2 z[64];
#pragma unroll
  for (int n = 0; n < 64; ++n) {
    const int m = bitrev6(n);
    z[n] = __floats2half2_rn(TBL.win[2 * m] * base[(2 * m) * C_],
                             TBL.win[2 * m + 1] * base[(2 * m + 1) * C_]);
  }

  // ---- 64-point complex DIT FFT, f16 packed butterflies ----
#pragma unroll
  for (int s = 0; s < 6; ++s) {
    const int half = 1 << s;
    const int len = half << 1;
#pragma unroll
    for (int j = 0; j < half; ++j) {
      const float wr = TBL.twr[j << (5 - s)];
      const float wi = TBL.twi[j << (5 - s)];
#pragma unroll
      for (int base2 = 0; base2 < 64; base2 += len) {
        const int a = base2 + j;
        const int b2 = a + half;
        const __half2 t = chmul(wr, wi, z[b2]);
        const __half2 za = z[a];
        z[b2] = __hsub2(za, t);
        z[a] = __hadd2(za, t);
      }
    }
  }

  // emit to LDS tile (lds_o layout == block's contiguous output region)
  float* lbase = lds_o + wv * (F_ * C_) + c;
  auto emit = [&](int f, float2 X) {
    const float2 d = make_float2(X.x - mu.x, X.y - mu.y);
    lbase[f * C_] = fast_sqrt(__builtin_fmaf(d.x, d.x, d.y * d.y)) * is;
  };

  // ---- real-FFT unpack in f32 (bins scaled 2x; compensated in mu/is) ----
  {
    const float2 z0 = __half22float2(z[0]);
    emit(0, make_float2(2.0f * (z0.x + z0.y), 0.0f));
    emit(64, make_float2(2.0f * (z0.x - z0.y), 0.0f));
    const float2 z32 = __half22float2(z[32]);
    emit(32, make_float2(2.0f * z32.x, -2.0f * z32.y));
  }
#pragma unroll
  for (int k = 1; k < 32; ++k) {
    const float2 zk = __half22float2(z[k]);
    const float2 zm = __half22float2(z[64 - k]);
    const float2 e = make_float2(zk.x + zm.x, zk.y - zm.y);
    const float2 o = make_float2(zk.y + zm.y, zm.x - zk.x);
    const float cr = TBL.cur[k], ci = TBL.cui[k];
    const float2 wO = make_float2(__builtin_fmaf(ci, -o.y, cr * o.x),
                                  __builtin_fmaf(ci, o.x, cr * o.y));
    emit(k, make_float2(e.x + wO.x, e.y + wO.y));
    emit(64 - k, make_float2(e.x - wO.x, wO.y - e.y));
  }

  // ---- drain: contiguous 33KB block region, ext-vec float4 nt stores ----
  __syncthreads();
  const f32x4_t* lsrc = reinterpret_cast<const f32x4_t*>(lds_o);
  f32x4_t* gdst =
      reinterpret_cast<f32x4_t*>(out + ((size_t)(b * L_ + l0)) * F_ * C_);
#pragma unroll 4
  for (int i = tid; i < (2 * F_ * C_) / 4; i += 128)
    __builtin_nontemporal_store(lsrc[i], &gdst[i]);
}

extern "C" void kernel_launch(void* const* d_in, const int* in_sizes, int n_in,
                              void* d_out, int out_size, void* d_ws, size_t ws_size,
                              hipStream_t stream) {
  const float* seq = (const float*)d_in[0];
  float* out = (float*)d_out;
  float* ws = (float*)d_ws;
  float* acc = ws;          // 3072 floats
  float* pad = ws + 4096;   // 16*640*64 = 655360 floats (2.62 MB)

  // 3 dispatches total (memset folded into pad kernel)
  fe_pad_kernel<<<(B_ * LP * C_) / 256, 256, 0, stream>>>(seq, pad, acc);
  fe_reduce_kernel<<<(B_ * L_) / 4, 256, 0, stream>>>(pad, acc);
  // 2 frames per 128-thread block; block output = contiguous 33KB
  fe_write_kernel<<<(B_ * L_) / 2, 128, 0, stream>>>(pad, acc, out);
}

// Round 21
// 61.001 us; speedup vs baseline: 1.1540x; 1.0375x over previous
//
#include <hip/hip_runtime.h>
#include <hip/hip_fp16.h>
#include <math.h>

// FreqEmbedding: seq [16,512,64] f32 -> out [16,512,65,64] f32
// reflect-pad(64) -> hanning(128) frames -> rfft(128) -> complex standardize
// over (L,F) per (B,C) -> abs.
//
// Pass 0 (pad): materialize reflect-padded input [16,640,64]; zeroes acc.
// Pass A (reduce): Parseval identities, f32 exact (mu/sigma exact).
// Pass B (write): R17's f16-state monolithic FFT + R21 SINGLE CHANGE:
//   __launch_bounds__(256,4) (VGPR cap 128). R5's (256,4) spilled because
//   f32 state = 128 regs + temps; f16 state = 64 regs + temps -> plausibly
//   fits 128. This is the one never-run occupancy experiment: write kernel
//   VALU issue = ~14us, store drain = ~22us, yet runs ~46us => ~30% issue
//   efficiency; everything except true-occupancy has been refuted
//   (stores R13/R20, I$ R8, L1 R16, restructure R6/R9-R12, MFMA R18).
//   Also: window applied as packed hmul2 after cvt_pk (saves 64 f32 muls).

#define B_ 16
#define L_ 512
#define C_ 64
#define W_ 128
#define F_ 65
#define LP 640  // padded length
#define NLF (L_ * F_)  // 33280

// ---------- compile-time trig tables (fold to VALU literals) ----------
constexpr double kPI = 3.14159265358979323846;

constexpr double csin_(double x) {
  while (x > kPI) x -= 2.0 * kPI;
  while (x < -kPI) x += 2.0 * kPI;
  double t = x, s = x, x2 = x * x;
  for (int i = 1; i <= 24; ++i) {
    t *= -x2 / ((2.0 * i) * (2.0 * i + 1.0));
    s += t;
  }
  return s;
}
constexpr double ccos_(double x) { return csin_(kPI / 2.0 - x); }

constexpr int bitrev6(int n) {
  int r = 0;
  for (int i = 0; i < 6; ++i) r |= ((n >> i) & 1) << (5 - i);
  return r;
}

struct Tables {
  float win[128];         // hanning w_n
  float walt[128];        // (-1)^n w_n
  float w2[128];          // w_n^2
  float wg[128];          // w_n * G_n
  float twr[32], twi[32]; // exp(-2*pi*i*j/64)
  float cur[32], cui[32]; // exp(-2*pi*i*k/128), k=0..31
  constexpr Tables() : win(), walt(), w2(), wg(), twr(), twi(), cur(), cui() {
    for (int n = 0; n < 128; ++n) {
      const double wd = 0.5 - 0.5 * ccos_(2.0 * kPI * n / 127.0);
      win[n] = (float)wd;
      walt[n] = (n & 1) ? (float)(-wd) : (float)wd;
      w2[n] = (float)(wd * wd);
      if (n == 0) {
        wg[n] = 0.0f;
      } else {
        // G_n = sin(pi n/2) * sin(65 pi n/128) / sin(pi n/128)
        const double G = csin_(kPI * n / 2.0) * csin_(65.0 * kPI * n / 128.0) /
                         csin_(kPI * n / 128.0);
        wg[n] = (float)(wd * G);
      }
    }
    for (int j = 0; j < 32; ++j) {
      twr[j] = (float)ccos_(2.0 * kPI * j / 64.0);
      twi[j] = (float)(-csin_(2.0 * kPI * j / 64.0));
    }
    for (int k = 0; k < 32; ++k) {
      cur[k] = (float)ccos_(2.0 * kPI * k / 128.0);
      cui[k] = (float)(-csin_(2.0 * kPI * k / 128.0));
    }
  }
};
constexpr Tables TBL{};

// branchless reflect into [0,512) for t in [-64, 575]
__device__ __forceinline__ int refl(int t) {
  const int a = max(t, -t);
  return min(a, 1022 - a);
}

__device__ __forceinline__ float fast_sqrt(float x) {
  float r;
  asm("v_sqrt_f32 %0, %1" : "=v"(r) : "v"(x));
  return r;
}

// packed f16 complex multiply: (wr + i*wi) * v, v = half2(re, im)
__device__ __forceinline__ __half2 chmul(float wr, float wi, __half2 v) {
  const __half2 w2r = __floats2half2_rn(wr, wr);     // literal
  const __half2 w2i = __floats2half2_rn(-wi, wi);    // literal
  const __half2 vsw = __lowhigh2highlow(v);          // (im, re)
  return __hfma2(w2i, vsw, __hmul2(w2r, v));
}

// ---------------- Pass 0: pad materialize + acc zero ----------------
__global__ void __launch_bounds__(256)
fe_pad_kernel(const float* __restrict__ seq, float* __restrict__ pad,
              float* __restrict__ acc) {
  const int idx = blockIdx.x * 256 + threadIdx.x;  // b*LP*C + t*C + c
  if (idx < 3072) acc[idx] = 0.0f;  // zero accumulators (reduce runs after)
  const int c = idx & 63;
  const int row = idx >> 6;  // b*LP + t
  const int b = row / LP;
  const int t = row - b * LP;
  const int s = refl(t - 64);
  pad[idx] = seq[(b * L_ + s) * C_ + c];
}

// ws layout (floats): [0..1023] sum_re, [1024..2047] sum_im, [2048..3071] sum_sq,
//                     [4096 ..] padded input [16][640][64]
// ---------------- Pass A: Parseval reduce (f32 exact) ----------------
__global__ void __launch_bounds__(256)
fe_reduce_kernel(const float* __restrict__ pad, float* __restrict__ acc) {
  const int p = blockIdx.x * 4 + (threadIdx.x >> 6);
  const int b = __builtin_amdgcn_readfirstlane(p >> 9);
  const int l = __builtin_amdgcn_readfirstlane(p & (L_ - 1));
  const int c = threadIdx.x & 63;

  const float* base = pad + ((size_t)(b * LP + l)) * C_ + c;

  float2 a0 = make_float2(0.f, 0.f), a1 = a0, a2 = a0, a3 = a0;
#pragma unroll
  for (int n = 0; n < 64; ++n) {
    const float2 v = make_float2(base[(2 * n) * C_], base[(2 * n + 1) * C_]);
    a0.x = __builtin_fmaf(TBL.win[2 * n], v.x, a0.x);
    a0.y = __builtin_fmaf(TBL.win[2 * n + 1], v.y, a0.y);
    a1.x = __builtin_fmaf(TBL.walt[2 * n], v.x, a1.x);
    a1.y = __builtin_fmaf(TBL.walt[2 * n + 1], v.y, a1.y);
    const float2 wv = make_float2(TBL.w2[2 * n] * v.x, TBL.w2[2 * n + 1] * v.y);
    a2.x = __builtin_fmaf(wv.x, v.x, a2.x);
    a2.y = __builtin_fmaf(wv.y, v.y, a2.y);
    a3.x = __builtin_fmaf(TBL.wg[2 * n], v.x, a3.x);
    a3.y = __builtin_fmaf(TBL.wg[2 * n + 1], v.y, a3.y);
  }
  const float x0 = a0.x + a0.y;
  const float x64 = a1.x + a1.y;
  const float p2 = a2.x + a2.y;
  const float d2 = a3.x + a3.y;

  const float sre = 0.5f * (x0 + x64);
  const float sim = -d2;
  const float ssq = 64.0f * p2 + 0.5f * (x0 * x0 + x64 * x64);

  __shared__ float red[3][256];
  const int tid = threadIdx.x;
  red[0][tid] = sre;
  red[1][tid] = sim;
  red[2][tid] = ssq;
  __syncthreads();
  if (tid < 64) {
    const float a0s = red[0][tid] + red[0][tid + 64] + red[0][tid + 128] + red[0][tid + 192];
    const float a1s = red[1][tid] + red[1][tid + 64] + red[1][tid + 128] + red[1][tid + 192];
    const float a2s = red[2][tid] + red[2][tid + 64] + red[2][tid + 128] + red[2][tid + 192];
    const int g = b * C_ + tid;
    unsafeAtomicAdd(&acc[g], a0s);
    unsafeAtomicAdd(&acc[1024 + g], a1s);
    unsafeAtomicAdd(&acc[2048 + g], a2s);
  }
}

// ---------------- Pass B: f16 FFT, VGPR-capped for 4 waves/SIMD ----------------
__global__ void __launch_bounds__(256, 4)
fe_write_kernel(const float* __restrict__ pad, const float* __restrict__ acc,
                float* __restrict__ out) {
  const int tid = threadIdx.x;
  const int p = blockIdx.x * 4 + (tid >> 6);
  const int b = __builtin_amdgcn_readfirstlane(p >> 9);
  const int l = __builtin_amdgcn_readfirstlane(p & (L_ - 1));
  const int c = tid & 63;

  // fused finalize: true-scale sums -> constants matching the 2x bins
  const int g = b * C_ + c;
  const float invN = 1.0f / (float)NLF;
  const float sr = acc[g] * invN;
  const float si = acc[1024 + g] * invN;
  const float qq = acc[2048 + g] * invN;
  const float var = qq - sr * sr - si * si;
  const float2 mu = make_float2(2.0f * sr, 2.0f * si);
  const float is = 0.5f * rsqrtf(var);

  const float* base = pad + ((size_t)(b * LP + l)) * C_ + c;

  // ---- load bit-reversed, cvt_pk to half2, packed window multiply ----
  __half2 z[64];
#pragma unroll
  for (int n = 0; n < 64; ++n) {
    const int m = bitrev6(n);
    const __half2 wc = __floats2half2_rn(TBL.win[2 * m], TBL.win[2 * m + 1]);
    z[n] = __hmul2(__floats2half2_rn(base[(2 * m) * C_],
                                     base[(2 * m + 1) * C_]), wc);
  }

  // ---- 64-point complex DIT FFT, f16 packed butterflies ----
#pragma unroll
  for (int s = 0; s < 6; ++s) {
    const int half = 1 << s;
    const int len = half << 1;
#pragma unroll
    for (int j = 0; j < half; ++j) {
      const float wr = TBL.twr[j << (5 - s)];
      const float wi = TBL.twi[j << (5 - s)];
#pragma unroll
      for (int base2 = 0; base2 < 64; base2 += len) {
        const int a = base2 + j;
        const int b2 = a + half;
        const __half2 t = chmul(wr, wi, z[b2]);
        const __half2 za = z[a];
        z[b2] = __hsub2(za, t);
        z[a] = __hadd2(za, t);
      }
    }
  }

  float* obase = out + (((size_t)(b * L_ + l)) * F_) * C_ + c;
  auto emit = [&](int f, float2 X) {
    const float2 d = make_float2(X.x - mu.x, X.y - mu.y);
    const float amp = fast_sqrt(__builtin_fmaf(d.x, d.x, d.y * d.y)) * is;
    __builtin_nontemporal_store(amp, &obase[(size_t)f * C_]);
  };

  // ---- real-FFT unpack in f32 (bins scaled 2x; compensated in mu/is) ----
  {
    const float2 z0 = __half22float2(z[0]);
    emit(0, make_float2(2.0f * (z0.x + z0.y), 0.0f));
    emit(64, make_float2(2.0f * (z0.x - z0.y), 0.0f));
    const float2 z32 = __half22float2(z[32]);
    emit(32, make_float2(2.0f * z32.x, -2.0f * z32.y));
  }
#pragma unroll
  for (int k = 1; k < 32; ++k) {
    const float2 zk = __half22float2(z[k]);
    const float2 zm = __half22float2(z[64 - k]);
    const float2 e = make_float2(zk.x + zm.x, zk.y - zm.y);
    const float2 o = make_float2(zk.y + zm.y, zm.x - zk.x);
    const float cr = TBL.cur[k], ci = TBL.cui[k];
    const float2 wO = make_float2(__builtin_fmaf(ci, -o.y, cr * o.x),
                                  __builtin_fmaf(ci, o.x, cr * o.y));
    emit(k, make_float2(e.x + wO.x, e.y + wO.y));
    emit(64 - k, make_float2(e.x - wO.x, wO.y - e.y));
  }
}

extern "C" void kernel_launch(void* const* d_in, const int* in_sizes, int n_in,
                              void* d_out, int out_size, void* d_ws, size_t ws_size,
                              hipStream_t stream) {
  const float* seq = (const float*)d_in[0];
  float* out = (float*)d_out;
  float* ws = (float*)d_ws;
  float* acc = ws;          // 3072 floats
  float* pad = ws + 4096;   // 16*640*64 = 655360 floats (2.62 MB)

  // 3 dispatches total (memset folded into pad kernel)
  fe_pad_kernel<<<(B_ * LP * C_) / 256, 256, 0, stream>>>(seq, pad, acc);
  const int nblocks = (B_ * L_) / 4;  // 2048 blocks, 4 (b,l) pairs each
  fe_reduce_kernel<<<nblocks, 256, 0, stream>>>(pad, acc);
  fe_write_kernel<<<nblocks, 256, 0, stream>>>(pad, acc, out);
}

// Round 22
// 55.826 us; speedup vs baseline: 1.2609x; 1.0927x over previous
//
#include <hip/hip_runtime.h>
#include <hip/hip_fp16.h>
#include <math.h>

// FreqEmbedding: seq [16,512,64] f32 -> out [16,512,65,64] f32
// reflect-pad(64) -> hanning(128) frames -> rfft(128) -> complex standardize
// over (L,F) per (B,C) -> abs.
//
// FINAL (R22 = R17 verbatim, the 21-round best at 56.4us):
// Pass 0 (pad): materialize reflect-padded input [16,640,64]; zeroes acc.
// Pass A (reduce): Parseval identities, f32 exact (mu/sigma exact), packed.
// Pass B (write): monolithic 64-pt FFT, f16-packed state (64 VGPR),
//   pk-f16 butterflies, f32 unpack/standardize, nt-stores, fast v_sqrt.
// Refuted levers (R4-R21): store path/locality, I$, L1 thrash, occupancy
//   (state halving + all launch-bounds variants), MFMA DFT, 6 restructures,
//   LDS staging both directions. Proven: Parseval reduce, nt+fast-sqrt,
//   packed-issue butterflies, memset fold, f16 state.

#define B_ 16
#define L_ 512
#define C_ 64
#define W_ 128
#define F_ 65
#define LP 640  // padded length
#define NLF (L_ * F_)  // 33280

// ---------- compile-time trig tables (fold to VALU literals) ----------
constexpr double kPI = 3.14159265358979323846;

constexpr double csin_(double x) {
  while (x > kPI) x -= 2.0 * kPI;
  while (x < -kPI) x += 2.0 * kPI;
  double t = x, s = x, x2 = x * x;
  for (int i = 1; i <= 24; ++i) {
    t *= -x2 / ((2.0 * i) * (2.0 * i + 1.0));
    s += t;
  }
  return s;
}
constexpr double ccos_(double x) { return csin_(kPI / 2.0 - x); }

constexpr int bitrev6(int n) {
  int r = 0;
  for (int i = 0; i < 6; ++i) r |= ((n >> i) & 1) << (5 - i);
  return r;
}

struct Tables {
  float win[128];         // hanning w_n
  float walt[128];        // (-1)^n w_n
  float w2[128];          // w_n^2
  float wg[128];          // w_n * G_n
  float twr[32], twi[32]; // exp(-2*pi*i*j/64)
  float cur[32], cui[32]; // exp(-2*pi*i*k/128), k=0..31
  constexpr Tables() : win(), walt(), w2(), wg(), twr(), twi(), cur(), cui() {
    for (int n = 0; n < 128; ++n) {
      const double wd = 0.5 - 0.5 * ccos_(2.0 * kPI * n / 127.0);
      win[n] = (float)wd;
      walt[n] = (n & 1) ? (float)(-wd) : (float)wd;
      w2[n] = (float)(wd * wd);
      if (n == 0) {
        wg[n] = 0.0f;
      } else {
        // G_n = sin(pi n/2) * sin(65 pi n/128) / sin(pi n/128)
        const double G = csin_(kPI * n / 2.0) * csin_(65.0 * kPI * n / 128.0) /
                         csin_(kPI * n / 128.0);
        wg[n] = (float)(wd * G);
      }
    }
    for (int j = 0; j < 32; ++j) {
      twr[j] = (float)ccos_(2.0 * kPI * j / 64.0);
      twi[j] = (float)(-csin_(2.0 * kPI * j / 64.0));
    }
    for (int k = 0; k < 32; ++k) {
      cur[k] = (float)ccos_(2.0 * kPI * k / 128.0);
      cui[k] = (float)(-csin_(2.0 * kPI * k / 128.0));
    }
  }
};
constexpr Tables TBL{};

// branchless reflect into [0,512) for t in [-64, 575]
__device__ __forceinline__ int refl(int t) {
  const int a = max(t, -t);
  return min(a, 1022 - a);
}

__device__ __forceinline__ float fast_sqrt(float x) {
  float r;
  asm("v_sqrt_f32 %0, %1" : "=v"(r) : "v"(x));
  return r;
}

// packed f16 complex multiply: (wr + i*wi) * v, v = half2(re, im)
__device__ __forceinline__ __half2 chmul(float wr, float wi, __half2 v) {
  const __half2 w2r = __floats2half2_rn(wr, wr);     // literal
  const __half2 w2i = __floats2half2_rn(-wi, wi);    // literal
  const __half2 vsw = __lowhigh2highlow(v);          // (im, re)
  return __hfma2(w2i, vsw, __hmul2(w2r, v));
}

// ---------------- Pass 0: pad materialize + acc zero ----------------
__global__ void __launch_bounds__(256)
fe_pad_kernel(const float* __restrict__ seq, float* __restrict__ pad,
              float* __restrict__ acc) {
  const int idx = blockIdx.x * 256 + threadIdx.x;  // b*LP*C + t*C + c
  if (idx < 3072) acc[idx] = 0.0f;  // zero accumulators (reduce runs after)
  const int c = idx & 63;
  const int row = idx >> 6;  // b*LP + t
  const int b = row / LP;
  const int t = row - b * LP;
  const int s = refl(t - 64);
  pad[idx] = seq[(b * L_ + s) * C_ + c];
}

// ws layout (floats): [0..1023] sum_re, [1024..2047] sum_im, [2048..3071] sum_sq,
//                     [4096 ..] padded input [16][640][64]
// ---------------- Pass A: Parseval reduce (f32 exact) ----------------
__global__ void __launch_bounds__(256)
fe_reduce_kernel(const float* __restrict__ pad, float* __restrict__ acc) {
  const int p = blockIdx.x * 4 + (threadIdx.x >> 6);
  const int b = __builtin_amdgcn_readfirstlane(p >> 9);
  const int l = __builtin_amdgcn_readfirstlane(p & (L_ - 1));
  const int c = threadIdx.x & 63;

  const float* base = pad + ((size_t)(b * LP + l)) * C_ + c;

  float2 a0 = make_float2(0.f, 0.f), a1 = a0, a2 = a0, a3 = a0;
#pragma unroll
  for (int n = 0; n < 64; ++n) {
    const float2 v = make_float2(base[(2 * n) * C_], base[(2 * n + 1) * C_]);
    a0.x = __builtin_fmaf(TBL.win[2 * n], v.x, a0.x);
    a0.y = __builtin_fmaf(TBL.win[2 * n + 1], v.y, a0.y);
    a1.x = __builtin_fmaf(TBL.walt[2 * n], v.x, a1.x);
    a1.y = __builtin_fmaf(TBL.walt[2 * n + 1], v.y, a1.y);
    const float2 wv = make_float2(TBL.w2[2 * n] * v.x, TBL.w2[2 * n + 1] * v.y);
    a2.x = __builtin_fmaf(wv.x, v.x, a2.x);
    a2.y = __builtin_fmaf(wv.y, v.y, a2.y);
    a3.x = __builtin_fmaf(TBL.wg[2 * n], v.x, a3.x);
    a3.y = __builtin_fmaf(TBL.wg[2 * n + 1], v.y, a3.y);
  }
  const float x0 = a0.x + a0.y;
  const float x64 = a1.x + a1.y;
  const float p2 = a2.x + a2.y;
  const float d2 = a3.x + a3.y;

  const float sre = 0.5f * (x0 + x64);
  const float sim = -d2;
  const float ssq = 64.0f * p2 + 0.5f * (x0 * x0 + x64 * x64);

  __shared__ float red[3][256];
  const int tid = threadIdx.x;
  red[0][tid] = sre;
  red[1][tid] = sim;
  red[2][tid] = ssq;
  __syncthreads();
  if (tid < 64) {
    const float a0s = red[0][tid] + red[0][tid + 64] + red[0][tid + 128] + red[0][tid + 192];
    const float a1s = red[1][tid] + red[1][tid + 64] + red[1][tid + 128] + red[1][tid + 192];
    const float a2s = red[2][tid] + red[2][tid + 64] + red[2][tid + 128] + red[2][tid + 192];
    const int g = b * C_ + tid;
    unsafeAtomicAdd(&acc[g], a0s);
    unsafeAtomicAdd(&acc[1024 + g], a1s);
    unsafeAtomicAdd(&acc[2048 + g], a2s);
  }
}

// ---------------- Pass B: monolithic FFT, f16-packed state ----------------
__global__ void __launch_bounds__(256)
fe_write_kernel(const float* __restrict__ pad, const float* __restrict__ acc,
                float* __restrict__ out) {
  const int tid = threadIdx.x;
  const int p = blockIdx.x * 4 + (tid >> 6);
  const int b = __builtin_amdgcn_readfirstlane(p >> 9);
  const int l = __builtin_amdgcn_readfirstlane(p & (L_ - 1));
  const int c = tid & 63;

  // fused finalize: true-scale sums -> constants matching the 2x bins
  const int g = b * C_ + c;
  const float invN = 1.0f / (float)NLF;
  const float sr = acc[g] * invN;
  const float si = acc[1024 + g] * invN;
  const float qq = acc[2048 + g] * invN;
  const float var = qq - sr * sr - si * si;
  const float2 mu = make_float2(2.0f * sr, 2.0f * si);
  const float is = 0.5f * rsqrtf(var);

  const float* base = pad + ((size_t)(b * LP + l)) * C_ + c;

  // ---- load in bit-reversed order, window in f32, pack to half2 ----
  __half2 z[64];
#pragma unroll
  for (int n = 0; n < 64; ++n) {
    const int m = bitrev6(n);
    z[n] = __floats2half2_rn(TBL.win[2 * m] * base[(2 * m) * C_],
                             TBL.win[2 * m + 1] * base[(2 * m + 1) * C_]);
  }

  // ---- 64-point complex DIT FFT, f16 packed butterflies ----
#pragma unroll
  for (int s = 0; s < 6; ++s) {
    const int half = 1 << s;
    const int len = half << 1;
#pragma unroll
    for (int j = 0; j < half; ++j) {
      const float wr = TBL.twr[j << (5 - s)];
      const float wi = TBL.twi[j << (5 - s)];
#pragma unroll
      for (int base2 = 0; base2 < 64; base2 += len) {
        const int a = base2 + j;
        const int b2 = a + half;
        const __half2 t = chmul(wr, wi, z[b2]);
        const __half2 za = z[a];
        z[b2] = __hsub2(za, t);
        z[a] = __hadd2(za, t);
      }
    }
  }

  float* obase = out + (((size_t)(b * L_ + l)) * F_) * C_ + c;
  auto emit = [&](int f, float2 X) {
    const float2 d = make_float2(X.x - mu.x, X.y - mu.y);
    const float amp = fast_sqrt(__builtin_fmaf(d.x, d.x, d.y * d.y)) * is;
    __builtin_nontemporal_store(amp, &obase[(size_t)f * C_]);
  };

  // ---- real-FFT unpack in f32 (bins scaled 2x; compensated in mu/is) ----
  {
    const float2 z0 = __half22float2(z[0]);
    emit(0, make_float2(2.0f * (z0.x + z0.y), 0.0f));
    emit(64, make_float2(2.0f * (z0.x - z0.y), 0.0f));
    const float2 z32 = __half22float2(z[32]);
    emit(32, make_float2(2.0f * z32.x, -2.0f * z32.y));
  }
#pragma unroll
  for (int k = 1; k < 32; ++k) {
    const float2 zk = __half22float2(z[k]);
    const float2 zm = __half22float2(z[64 - k]);
    const float2 e = make_float2(zk.x + zm.x, zk.y - zm.y);
    const float2 o = make_float2(zk.y + zm.y, zm.x - zk.x);
    const float cr = TBL.cur[k], ci = TBL.cui[k];
    const float2 wO = make_float2(__builtin_fmaf(ci, -o.y, cr * o.x),
                                  __builtin_fmaf(ci, o.x, cr * o.y));
    emit(k, make_float2(e.x + wO.x, e.y + wO.y));
    emit(64 - k, make_float2(e.x - wO.x, wO.y - e.y));
  }
}

extern "C" void kernel_launch(void* const* d_in, const int* in_sizes, int n_in,
                              void* d_out, int out_size, void* d_ws, size_t ws_size,
                              hipStream_t stream) {
  const float* seq = (const float*)d_in[0];
  float* out = (float*)d_out;
  float* ws = (float*)d_ws;
  float* acc = ws;          // 3072 floats
  float* pad = ws + 4096;   // 16*640*64 = 655360 floats (2.62 MB)

  // 3 dispatches total (memset folded into pad kernel)
  fe_pad_kernel<<<(B_ * LP * C_) / 256, 256, 0, stream>>>(seq, pad, acc);
  const int nblocks = (B_ * L_) / 4;  // 2048 blocks, 4 (b,l) pairs each
  fe_reduce_kernel<<<nblocks, 256, 0, stream>>>(pad, acc);
  fe_write_kernel<<<nblocks, 256, 0, stream>>>(pad, acc, out);
}